// Round 1
// 749.084 us; speedup vs baseline: 1.1248x; 1.1248x over previous
//
#include <hip/hip_runtime.h>

#define E_CONST 500000
#define N_CONST 100000

typedef __attribute__((ext_vector_type(8))) short bf16x8;
typedef __attribute__((ext_vector_type(4))) float f32x4;
typedef __attribute__((ext_vector_type(4))) unsigned u32x4;

// ---------------------------------------------------------------------------
// Prep: swizzle w1 (384x128) and w2 (128x128) fp32 -> bf16 MFMA B-fragments.
// B-frag for tile (kk, nn): lane l holds B[kk*32 + (l>>4)*8 + j][nn*16 + (l&15)],
// stored lane-major: ws[frag*512 + l*8 + j].  w1: frags 0..95, w2: frags 96..127.
// ---------------------------------------------------------------------------
__global__ __launch_bounds__(256) void prep_weights(const float* __restrict__ w1,
                                                    const float* __restrict__ w2,
                                                    short* __restrict__ ws) {
    int idx  = blockIdx.x * 256 + threadIdx.x;   // 0..65535
    int frag = idx >> 9;
    int r    = idx & 511;
    int lane = r >> 3, j = r & 7;
    const float* w;
    int fi;
    if (frag < 96) { w = w1; fi = frag; }
    else           { w = w2; fi = frag - 96; }
    int kk = fi >> 3, nn = fi & 7;
    int k = kk * 32 + (lane >> 4) * 8 + j;
    int n = nn * 16 + (lane & 15);
    unsigned u = __float_as_uint(w[k * 128 + n]);
    u = u + 0x7FFFu + ((u >> 16) & 1u);          // RNE to bf16
    ws[idx] = (short)(u >> 16);
}

// nfeat passthrough -> second tuple output
__global__ __launch_bounds__(256) void copy_nfeat(const float* __restrict__ nfeat,
                                                  float* __restrict__ out) {
    size_t idx = (size_t)(blockIdx.x * 256 + threadIdx.x) * 4;  // exact: 12.8M floats
    *(f32x4*)(out + idx) = *(const f32x4*)(nfeat + idx);
}

__device__ __forceinline__ unsigned pack_bf16_trunc(float lo, float hi) {
    // dst = { hi[31:16], lo[31:16] } in one v_perm_b32
    return __builtin_amdgcn_perm(__float_as_uint(hi), __float_as_uint(lo), 0x07060302u);
}

__device__ __forceinline__ bf16x8 pack8(f32x4 f0, f32x4 f1) {
    u32x4 pk;
    pk.x = pack_bf16_trunc(f0.x, f0.y);
    pk.y = pack_bf16_trunc(f0.z, f0.w);
    pk.z = pack_bf16_trunc(f1.x, f1.y);
    pk.w = pack_bf16_trunc(f1.z, f1.w);
    return __builtin_bit_cast(bf16x8, pk);
}

// ---------------------------------------------------------------------------
// Fused: gather-concat -> GEMM1(384->128) -> SiLU -> GEMM2(128->128) -> LN -> +efeat
// Block: 256 thr (4 waves), 64 edges. Wave nw owns output cols [nw*32, nw*32+32).
// Phase 0: cooperative staging of gathered nfeat rows into LDS (bf16), deep MLP.
// LN done from register-resident y via shfl partials (no ys LDS round trip).
// ---------------------------------------------------------------------------
__global__ __launch_bounds__(256, 2) void edge_mlp(
    const float* __restrict__ efeat, const float* __restrict__ nfeat,
    const int* __restrict__ src, const int* __restrict__ dst,
    const short* __restrict__ wsw,
    const float* __restrict__ b1, const float* __restrict__ b2,
    const float* __restrict__ gamma, const float* __restrict__ beta,
    float* __restrict__ out) {

    // As row stride 264 shorts = 528 B == 16 mod 128 -> conflict-free b128 frag reads
    __shared__ short As[64 * 264];     // staged nfeat[src]|nfeat[dst] per edge, bf16
    __shared__ short hs[64 * 136];     // h tile, bf16, +8 pad
    __shared__ float psum_s[256];      // per-row per-wave partial sums (64 x 4)
    __shared__ float psq_s[256];
    __shared__ float mu_s[64];
    __shared__ float rs_s[64];

    const int tid   = threadIdx.x;
    const int lane  = tid & 63;
    const int nw    = tid >> 6;      // wave 0..3
    const int l15   = lane & 15;
    const int quad  = lane >> 4;     // 0..3
    const int eBase = blockIdx.x * 64;

    // persistent weight fragments
    bf16x8 b1f[2][12];
    bf16x8 b2f[2][4];
#pragma unroll
    for (int t = 0; t < 2; ++t) {
        int nn = nw * 2 + t;
#pragma unroll
        for (int kk = 0; kk < 12; ++kk)
            b1f[t][kk] = *(const bf16x8*)(wsw + ((kk * 8 + nn) * 64 + lane) * 8);
#pragma unroll
        for (int kk = 0; kk < 4; ++kk)
            b2f[t][kk] = *(const bf16x8*)(wsw + 49152 + ((kk * 8 + nn) * 64 + lane) * 8);
    }
    const float bb1[2] = { b1[nw * 32 + l15], b1[nw * 32 + 16 + l15] };
    const float bb2[2] = { b2[nw * 32 + l15], b2[nw * 32 + 16 + l15] };
    const float gg[2]  = { gamma[nw * 32 + l15], gamma[nw * 32 + 16 + l15] };
    const float bt[2]  = { beta[nw * 32 + l15],  beta[nw * 32 + 16 + l15] };

    // ---- Phase 0: cooperative gather of nfeat[src]/nfeat[dst] rows -> As ----
    // 128 rows x 512B; each thread stages half a row (16 independent f32x4 loads).
    {
        int r  = tid >> 1;            // 0..127: rows 0-63 = src, 64-127 = dst
        int hf = tid & 1;             // half-row (64 floats)
        int e  = eBase + (r & 63);
        if (e >= E_CONST) e = E_CONST - 1;              // clamp tail
        int idx = (r < 64) ? src[e] : dst[e];           // wave-uniform branch
        const float* p = nfeat + (size_t)idx * 128 + hf * 64;
        short* wp = As + (r & 63) * 264 + (r >> 6) * 128 + hf * 64;
#pragma unroll 4
        for (int j = 0; j < 8; ++j) {
            f32x4 f0 = *(const f32x4*)(p + j * 8);
            f32x4 f1 = *(const f32x4*)(p + j * 8 + 4);
            *(bf16x8*)(wp + j * 8) = pack8(f0, f1);
        }
    }
    __syncthreads();

    // ---- GEMM1 + SiLU -> hs  (A: efeat direct + staged nfeat from LDS) ----
#pragma unroll 1
    for (int mt = 0; mt < 4; ++mt) {
        int e = eBase + mt * 16 + l15;
        if (e >= E_CONST) e = E_CONST - 1;              // clamp tail (stores guarded later)
        const float* pe = efeat + (size_t)e * 128 + quad * 8;
        const short* ap = As + (mt * 16 + l15) * 264 + quad * 8;

        f32x4 acc0 = {0.f, 0.f, 0.f, 0.f}, acc1 = {0.f, 0.f, 0.f, 0.f};
#pragma unroll
        for (int kk = 0; kk < 4; ++kk) {                // efeat part (dense, L2-hot)
            f32x4 f0 = *(const f32x4*)(pe + kk * 32);
            f32x4 f1 = *(const f32x4*)(pe + kk * 32 + 4);
            bf16x8 a = pack8(f0, f1);
            acc0 = __builtin_amdgcn_mfma_f32_16x16x32_bf16(a, b1f[0][kk], acc0, 0, 0, 0);
            acc1 = __builtin_amdgcn_mfma_f32_16x16x32_bf16(a, b1f[1][kk], acc1, 0, 0, 0);
        }
#pragma unroll
        for (int kk = 4; kk < 12; ++kk) {               // staged nfeat part (LDS)
            bf16x8 a = *(const bf16x8*)(ap + (kk - 4) * 32);
            acc0 = __builtin_amdgcn_mfma_f32_16x16x32_bf16(a, b1f[0][kk], acc0, 0, 0, 0);
            acc1 = __builtin_amdgcn_mfma_f32_16x16x32_bf16(a, b1f[1][kk], acc1, 0, 0, 0);
        }
#pragma unroll
        for (int t = 0; t < 2; ++t) {
            f32x4 acc = (t == 0) ? acc0 : acc1;
            int col = nw * 32 + t * 16 + l15;
#pragma unroll
            for (int i = 0; i < 4; ++i) {
                float x  = acc[i] + bb1[t];
                float sg = __builtin_amdgcn_rcpf(1.0f + __expf(-x));
                float h  = x * sg;                               // SiLU
                int row  = mt * 16 + quad * 4 + i;               // C layout: row=quad*4+i
                unsigned u = __float_as_uint(h);
                u = u + 0x7FFFu + ((u >> 16) & 1u);
                hs[row * 136 + col] = (short)(u >> 16);
            }
        }
    }
    __syncthreads();

    // ---- GEMM2 -> y in registers (fully unrolled: static reg indexing) ----
    f32x4 y0[4], y1[4];
#pragma unroll
    for (int mt = 0; mt < 4; ++mt) {
        int arow = mt * 16 + l15;
        f32x4 acc0 = {0.f, 0.f, 0.f, 0.f}, acc1 = {0.f, 0.f, 0.f, 0.f};
#pragma unroll
        for (int kk = 0; kk < 4; ++kk) {
            bf16x8 a = *(const bf16x8*)(hs + arow * 136 + kk * 32 + quad * 8);
            acc0 = __builtin_amdgcn_mfma_f32_16x16x32_bf16(a, b2f[0][kk], acc0, 0, 0, 0);
            acc1 = __builtin_amdgcn_mfma_f32_16x16x32_bf16(a, b2f[1][kk], acc1, 0, 0, 0);
        }
        f32x4 bv0 = { bb2[0], bb2[0], bb2[0], bb2[0] };
        f32x4 bv1 = { bb2[1], bb2[1], bb2[1], bb2[1] };
        y0[mt] = acc0 + bv0;
        y1[mt] = acc1 + bv1;
    }

    // ---- LN stats: in-register partials + shfl over the 16-lane col group ----
#pragma unroll
    for (int mt = 0; mt < 4; ++mt) {
#pragma unroll
        for (int i = 0; i < 4; ++i) {
            float a0 = y0[mt][i], a1 = y1[mt][i];
            float s = a0 + a1;
            float q = a0 * a0 + a1 * a1;
            s += __shfl_xor(s, 1);  q += __shfl_xor(q, 1);
            s += __shfl_xor(s, 2);  q += __shfl_xor(q, 2);
            s += __shfl_xor(s, 4);  q += __shfl_xor(q, 4);
            s += __shfl_xor(s, 8);  q += __shfl_xor(q, 8);
            if (l15 == 0) {
                int row = mt * 16 + quad * 4 + i;
                psum_s[row * 4 + nw] = s;
                psq_s [row * 4 + nw] = q;
            }
        }
    }
    __syncthreads();

    if (tid < 64) {
        f32x4 ps = *(const f32x4*)(psum_s + tid * 4);
        f32x4 pq = *(const f32x4*)(psq_s  + tid * 4);
        float mu = (ps.x + ps.y + ps.z + ps.w) * (1.0f / 128.0f);
        float m2 = (pq.x + pq.y + pq.z + pq.w) * (1.0f / 128.0f);
        mu_s[tid] = mu;
        rs_s[tid] = __builtin_amdgcn_rsqf(m2 - mu * mu + 1e-5f);
    }
    __syncthreads();

    // ---- normalize + gamma/beta + residual, stores from register y ----
#pragma unroll
    for (int mt = 0; mt < 4; ++mt) {
#pragma unroll
        for (int i = 0; i < 4; ++i) {
            int row = mt * 16 + quad * 4 + i;
            int e = eBase + row;
            if (e < E_CONST) {
                float mu = mu_s[row], rs = rs_s[row];
                int col0 = nw * 32 + l15;
                const float* pef = efeat + (size_t)e * 128;
                float* po = out + (size_t)e * 128;
                po[col0]      = (y0[mt][i] - mu) * rs * gg[0] + bt[0] + pef[col0];
                po[col0 + 16] = (y1[mt][i] - mu) * rs * gg[1] + bt[1] + pef[col0 + 16];
            }
        }
    }
}

extern "C" void kernel_launch(void* const* d_in, const int* in_sizes, int n_in,
                              void* d_out, int out_size, void* d_ws, size_t ws_size,
                              hipStream_t stream) {
    const float* efeat = (const float*)d_in[0];
    const float* nfeat = (const float*)d_in[1];
    const int*   src   = (const int*)d_in[2];
    const int*   dst   = (const int*)d_in[3];
    const float* w1    = (const float*)d_in[4];
    const float* b1    = (const float*)d_in[5];
    const float* w2    = (const float*)d_in[6];
    const float* b2    = (const float*)d_in[7];
    const float* gamma = (const float*)d_in[8];
    const float* beta  = (const float*)d_in[9];
    float* out = (float*)d_out;
    short* wsw = (short*)d_ws;

    hipLaunchKernelGGL(prep_weights, dim3(256), dim3(256), 0, stream, w1, w2, wsw);
    hipLaunchKernelGGL(copy_nfeat, dim3(12500), dim3(256), 0, stream,
                       nfeat, out + (size_t)E_CONST * 128);
    hipLaunchKernelGGL(edge_mlp, dim3((E_CONST + 63) / 64), dim3(256), 0, stream,
                       efeat, nfeat, src, dst, wsw, b1, b2, gamma, beta, out);
}